// Round 13
// baseline (323.172 us; speedup 1.0000x reference)
//
#include <hip/hip_runtime.h>
#include <hip/hip_fp16.h>

#define HW 65536
#define PW 256        // plane width

// Fast exact-gelu: erf via Abramowitz-Stegun 7.1.26 (|err| <= 1.5e-7).
__device__ __forceinline__ float gelu_f(float v) {
    float ax = fabsf(v) * 0.7071067811865476f;
    float t  = 1.0f / (1.0f + 0.3275911f * ax);
    float p  = t * (0.254829592f + t * (-0.284496736f + t * (1.421413741f
             + t * (-1.453152027f + t * 1.061405429f))));
    float e  = 1.0f - p * __expf(-ax * ax);
    e = copysignf(e, v);
    return 0.5f * v * (1.0f + e);
}

__device__ __forceinline__ unsigned pack2h(float a, float b) {
    __half2 h = __floats2half2_rn(a, b);
    return *reinterpret_cast<unsigned*>(&h);
}

__device__ __forceinline__ void unpack8(uint4 u, float* dst) {
    float2 f;
    f = __half22float2(*reinterpret_cast<__half2*>(&u.x)); dst[0] = f.x; dst[1] = f.y;
    f = __half22float2(*reinterpret_cast<__half2*>(&u.y)); dst[2] = f.x; dst[3] = f.y;
    f = __half22float2(*reinterpret_cast<__half2*>(&u.z)); dst[4] = f.x; dst[5] = f.y;
    f = __half22float2(*reinterpret_cast<__half2*>(&u.w)); dst[6] = f.x; dst[7] = f.y;
}

__device__ __forceinline__ float sgpr_f(float v) {
    union { float f; int i; } u;
    u.f = v;
    u.i = __builtin_amdgcn_readfirstlane(u.i);
    return u.f;
}

// acc(f32) += w(f32) * f16-half of h2 (packed u32), via v_fma_mix_f32 op_sel.
__device__ __forceinline__ void fma_mix_h(float& acc, float w, unsigned h2, int sel) {
    if (sel == 0)
        asm("v_fma_mix_f32 %0, %1, %2, %0 op_sel:[0,0,0] op_sel_hi:[0,1,0]"
            : "+v"(acc) : "v"(w), "v"(h2));
    else
        asm("v_fma_mix_f32 %0, %1, %2, %0 op_sel:[0,1,0] op_sel_hi:[0,1,0]"
            : "+v"(acc) : "v"(w), "v"(h2));
}

// ---------------- K0: pool x over H,W (partial sums, 4 blocks per plane) ------
__global__ __launch_bounds__(256) void k_pool_x(const float* __restrict__ x,
                                                float* __restrict__ partial) {
    __shared__ float red[256];
    const int t = threadIdx.x;
    const int blk = blockIdx.x;              // plane*4 + quarter
    const float* p = x + (size_t)blk * 16384;
    float s = 0.f;
    #pragma unroll
    for (int i = 0; i < 16; ++i) {
        float4 v = *reinterpret_cast<const float4*>(p + (i * 256 + t) * 4);
        s += v.x + v.y + v.z + v.w;
    }
    red[t] = s;
    __syncthreads();
    for (int off = 128; off > 0; off >>= 1) {
        if (t < off) red[t] += red[t + off];
        __syncthreads();
    }
    if (t == 0) partial[blk] = red[0];
}

// ------------- K1/K3: reduce partials -> routing -> mixed kernels -------------
__global__ __launch_bounds__(64) void k_route_mix(const float* __restrict__ partial,
                                                  const float* __restrict__ rw,
                                                  const float* __restrict__ rb,
                                                  const float* __restrict__ wexp,
                                                  float* __restrict__ wkout,
                                                  int taps, int parts) {
    __shared__ float pool_s[64];
    __shared__ float r_s[3];
    const int b = blockIdx.x, c = threadIdx.x;   // 64 threads = channels
    float s = 0.f;
    for (int q = 0; q < parts; ++q) s += partial[(b * 64 + c) * parts + q];
    pool_s[c] = s * (1.0f / 65536.0f);
    __syncthreads();
    if (c < 3) {
        float z = rb[c];
        #pragma unroll
        for (int i = 0; i < 64; ++i) z += pool_s[i] * rw[c * 64 + i];
        r_s[c] = 1.0f / (1.0f + expf(-z));
    }
    __syncthreads();
    const float r0 = r_s[0], r1 = r_s[1], r2 = r_s[2];
    for (int j = 0; j < taps; ++j) {
        wkout[(b * 64 + c) * taps + j] =
            r0 * wexp[(0 * 64 + c) * taps + j] +
            r1 * wexp[(1 * 64 + c) * taps + j] +
            r2 * wexp[(2 * 64 + c) * taps + j];
    }
}

// -------- K2: depthwise 5x5 pad2 + bias + gelu -> fp16, with tile sums --------
// (R7 version: global float4 loads, 8x8/thread, fast gelu — best measured conv5)
__global__ __launch_bounds__(256) void k_conv5(const float* __restrict__ x,
                                               const float* __restrict__ wk,
                                               const float* __restrict__ bias,
                                               __half* __restrict__ attn0,
                                               float* __restrict__ tilesum) {
    __shared__ float red[256];
    const int blk = blockIdx.x;              // plane*4 + tile (128x128 tiles)
    const int plane = blk >> 2;
    const int tile = blk & 3;
    const int c = plane & 63;
    const int oy0 = (tile >> 1) << 7;
    const int ox0 = (tile & 1) << 7;
    const int t = threadIdx.x;
    const int ox = ox0 + ((t & 15) << 3);    // 8-wide strip
    const int oy = oy0 + ((t >> 4) << 3);    // 8-tall
    const float* xp = x + (size_t)plane * HW;
    const float* wkp = wk + plane * 25;
    float w[25];
    #pragma unroll
    for (int i = 0; i < 25; ++i) w[i] = sgpr_f(wkp[i]);
    float acc[8][8];
    #pragma unroll
    for (int i = 0; i < 8; ++i)
        #pragma unroll
        for (int j = 0; j < 8; ++j) acc[i][j] = 0.f;

    #pragma unroll
    for (int r = 0; r < 12; ++r) {
        const int gy = oy - 2 + r;
        if (gy >= 0 && gy < 256) {
            const float* rp = xp + gy * PW + ox;
            float buf[16];
            float4 v;
            if (ox > 0) v = *reinterpret_cast<const float4*>(rp - 4);
            else        v = make_float4(0.f, 0.f, 0.f, 0.f);
            buf[0] = v.x; buf[1] = v.y; buf[2] = v.z; buf[3] = v.w;
            v = *reinterpret_cast<const float4*>(rp);
            buf[4] = v.x; buf[5] = v.y; buf[6] = v.z; buf[7] = v.w;
            v = *reinterpret_cast<const float4*>(rp + 4);
            buf[8] = v.x; buf[9] = v.y; buf[10] = v.z; buf[11] = v.w;
            if (ox < 248) v = *reinterpret_cast<const float4*>(rp + 8);
            else          v = make_float4(0.f, 0.f, 0.f, 0.f);
            buf[12] = v.x; buf[13] = v.y; buf[14] = v.z; buf[15] = v.w;
            #pragma unroll
            for (int i = 0; i < 8; ++i) {
                const int d = r - i;
                if (d >= 0 && d <= 4) {
                    #pragma unroll
                    for (int dx = 0; dx < 5; ++dx) {
                        const float wv = w[d * 5 + dx];
                        #pragma unroll
                        for (int j = 0; j < 8; ++j)
                            acc[i][j] += wv * buf[j + dx + 2];
                    }
                }
            }
        }
    }
    const float bs = bias[c];
    float lsum = 0.f;
    __half* op = attn0 + (size_t)plane * HW;
    #pragma unroll
    for (int i = 0; i < 8; ++i) {
        float g[8];
        #pragma unroll
        for (int j = 0; j < 8; ++j) {
            g[j] = gelu_f(acc[i][j] + bs);
            lsum += g[j];
        }
        uint4 st;
        st.x = pack2h(g[0], g[1]); st.y = pack2h(g[2], g[3]);
        st.z = pack2h(g[4], g[5]); st.w = pack2h(g[6], g[7]);
        *reinterpret_cast<uint4*>(op + (oy + i) * PW + ox) = st;
    }
    red[t] = lsum;
    __syncthreads();
    for (int off = 128; off > 0; off >>= 1) {
        if (t < off) red[t] += red[t + off];
        __syncthreads();
    }
    if (t == 0) tilesum[blk] = red[0];
}

// -------- K4: depthwise 7x7 dil3 pad9 + bias + gelu, fp16 -> fp16 -------------
// NO LDS: R7/R9/R12 were flat at ~90us across -40% VALU instr / -57% conflicts;
// the invariant was ~113k LDS-pipe cycles/CU (base + conflict traded 1:1).
// Direct global dwordx4 reads move the 2x read amplification to L1/L2.
// Geometry = R9 (64x128 tile, 4x64 map, 1 row x 32 cols, fma_mix, SGPR w).
__global__ __launch_bounds__(256, 4) void k_conv7(const __half* __restrict__ a0,
                                                  const float* __restrict__ wk,
                                                  const float* __restrict__ bias,
                                                  __half* __restrict__ attn1) {
    const int blk = blockIdx.x;              // plane*8 + tile (64-row x 128-col)
    const int plane = blk >> 3;
    const int tile = blk & 7;
    const int c = plane & 63;
    const int oy0 = (tile >> 1) << 6;        // 0,64,128,192
    const int ox0 = (tile & 1) << 7;         // 0,128
    const int t = threadIdx.x;
    const int tx = t & 3, ty = t >> 2;       // 4 x 64
    const int oxg = ox0 + (tx << 5);         // global col base of 32-col strip
    const int oy = oy0 + ty;                 // global output row
    const __half* ap = a0 + (size_t)plane * HW;

    float w[49];
    #pragma unroll
    for (int i = 0; i < 49; ++i) w[i] = sgpr_f(wk[plane * 49 + i]);

    float acc[32];
    #pragma unroll
    for (int j = 0; j < 32; ++j) acc[j] = 0.f;

    const uint4 z4 = make_uint4(0u, 0u, 0u, 0u);
    const bool lok = (oxg > 0);              // left halo in-bounds
    const bool rok = (oxg < 224);            // right halo in-bounds
    #pragma unroll
    for (int dyi = 0; dyi < 7; ++dyi) {
        const int gy = oy + 3 * dyi - 9;
        if (gy >= 0 && gy < 256) {
            // window halves [oxg-16, oxg+48): 8 x 16B loads
            const __half* rp = ap + gy * PW + oxg;
            unsigned hbuf[32];
            uint4 u;
            u = lok ? *reinterpret_cast<const uint4*>(rp - 16) : z4;
            *reinterpret_cast<uint4*>(&hbuf[0]) = u;
            u = lok ? *reinterpret_cast<const uint4*>(rp - 8) : z4;
            *reinterpret_cast<uint4*>(&hbuf[4]) = u;
            #pragma unroll
            for (int k = 0; k < 4; ++k)
                *reinterpret_cast<uint4*>(&hbuf[8 + (k << 2)]) =
                    *reinterpret_cast<const uint4*>(rp + (k << 3));
            u = rok ? *reinterpret_cast<const uint4*>(rp + 32) : z4;
            *reinterpret_cast<uint4*>(&hbuf[24]) = u;
            u = rok ? *reinterpret_cast<const uint4*>(rp + 40) : z4;
            *reinterpret_cast<uint4*>(&hbuf[28]) = u;
            #pragma unroll
            for (int dxi = 0; dxi < 7; ++dxi) {
                const float wv = w[dyi * 7 + dxi];
                const int o = 7 + 3 * dxi;   // half offset (rel window start +16)
                #pragma unroll
                for (int j = 0; j < 32; ++j) {
                    const int h = o + j;     // compile-time after unroll
                    fma_mix_h(acc[j], wv, hbuf[h >> 1], h & 1);
                }
            }
        }
    }

    const float bs = bias[c];
    __half* op = attn1 + (size_t)plane * HW + (size_t)oy * PW + oxg;
    #pragma unroll
    for (int q = 0; q < 4; ++q) {
        float g[8];
        #pragma unroll
        for (int j = 0; j < 8; ++j) g[j] = gelu_f(acc[q * 8 + j] + bs);
        uint4 st;
        st.x = pack2h(g[0], g[1]); st.y = pack2h(g[2], g[3]);
        st.z = pack2h(g[4], g[5]); st.w = pack2h(g[6], g[7]);
        *reinterpret_cast<uint4*>(op + (q << 3)) = st;
    }
}

// -------- K5: 1x1 channel mix + bias, then out = x * attn ---------------------
__global__ __launch_bounds__(256) void k_mix(const __half* __restrict__ attn1,
                                             const float* __restrict__ wpm,
                                             const float* __restrict__ bp,
                                             const float* __restrict__ x,
                                             float* __restrict__ out) {
    __shared__ __half A_s[64][256];
    __shared__ float wpT[64][64];
    const int t = threadIdx.x;
    const int blk = blockIdx.x;
    const int b = blk >> 8;
    const int p0g = (blk & 255) << 8;        // 256-pixel chunk
    #pragma unroll
    for (int it = 0; it < 8; ++it) {
        const int ci = it * 256 + t;
        const int row = ci >> 5;
        const int off = (ci & 31) << 3;
        uint4 u = *reinterpret_cast<const uint4*>(attn1 + (size_t)(b * 64 + row) * HW + p0g + off);
        *reinterpret_cast<uint4*>(&A_s[row][off]) = u;
    }
    #pragma unroll
    for (int j = 0; j < 16; ++j) {
        const int idx = j * 256 + t;
        const int cc = idx & 63;
        const int oo = idx >> 6;
        wpT[cc][oo] = wpm[oo * 64 + cc];     // coalesced read, conflicted write (once)
    }
    __syncthreads();
    const int o0 = (t >> 5) << 3;
    const int p0 = (t & 31) << 3;
    float acc[8][8];
    #pragma unroll
    for (int i = 0; i < 8; ++i)
        #pragma unroll
        for (int j = 0; j < 8; ++j) acc[i][j] = 0.f;
    #pragma unroll 4
    for (int cc = 0; cc < 64; ++cc) {
        float4 wa = *reinterpret_cast<const float4*>(&wpT[cc][o0]);
        float4 wb = *reinterpret_cast<const float4*>(&wpT[cc][o0 + 4]);
        const float wv[8] = {wa.x, wa.y, wa.z, wa.w, wb.x, wb.y, wb.z, wb.w};
        float af[8];
        uint4 u = *reinterpret_cast<const uint4*>(&A_s[cc][p0]);
        unpack8(u, af);
        #pragma unroll
        for (int oo = 0; oo < 8; ++oo) {
            const float wvv = wv[oo];
            #pragma unroll
            for (int pp = 0; pp < 8; ++pp) acc[oo][pp] += wvv * af[pp];
        }
    }
    #pragma unroll
    for (int oo = 0; oo < 8; ++oo) {
        const int o = o0 + oo;
        const float bb = bp[o];
        const size_t base = (size_t)(b * 64 + o) * HW + p0g + p0;
        float4 x0 = *reinterpret_cast<const float4*>(x + base);
        float4 x1 = *reinterpret_cast<const float4*>(x + base + 4);
        float4 r0, r1;
        r0.x = x0.x * (acc[oo][0] + bb); r0.y = x0.y * (acc[oo][1] + bb);
        r0.z = x0.z * (acc[oo][2] + bb); r0.w = x0.w * (acc[oo][3] + bb);
        r1.x = x1.x * (acc[oo][4] + bb); r1.y = x1.y * (acc[oo][5] + bb);
        r1.z = x1.z * (acc[oo][6] + bb); r1.w = x1.w * (acc[oo][7] + bb);
        *reinterpret_cast<float4*>(out + base) = r0;
        *reinterpret_cast<float4*>(out + base + 4) = r1;
    }
}

extern "C" void kernel_launch(void* const* d_in, const int* in_sizes, int n_in,
                              void* d_out, int out_size, void* d_ws, size_t ws_size,
                              hipStream_t stream) {
    const float* x   = (const float*)d_in[0];
    const float* w0  = (const float*)d_in[1];
    const float* b0  = (const float*)d_in[2];
    const float* r0w = (const float*)d_in[3];
    const float* r0b = (const float*)d_in[4];
    const float* w1  = (const float*)d_in[5];
    const float* b1  = (const float*)d_in[6];
    const float* r1w = (const float*)d_in[7];
    const float* r1b = (const float*)d_in[8];
    const float* wpm = (const float*)d_in[9];
    const float* bp  = (const float*)d_in[10];
    float* out = (float*)d_out;

    // workspace layout (needs ~134.4 MB)
    char* ws = (char*)d_ws;
    __half* attn0   = (__half*)(ws);                       // 64 MB
    __half* attn1   = (__half*)(ws + 67108864);            // 64 MB
    float* partial0 = (float*)(ws + 134217728);            // 2048 f32
    float* tilesum1 = (float*)(ws + 134217728 + 8192);     // 2048 f32
    float* wk0      = (float*)(ws + 134217728 + 16384);    // 512*25 f32
    float* wk1      = (float*)(ws + 134217728 + 16384 + 51200); // 512*49 f32

    k_pool_x<<<2048, 256, 0, stream>>>(x, partial0);
    k_route_mix<<<8, 64, 0, stream>>>(partial0, r0w, r0b, w0, wk0, 25, 4);
    k_conv5<<<2048, 256, 0, stream>>>(x, wk0, b0, attn0, tilesum1);
    k_route_mix<<<8, 64, 0, stream>>>(tilesum1, r1w, r1b, w1, wk1, 49, 4);
    k_conv7<<<4096, 256, 0, stream>>>(attn0, wk1, b1, attn1);
    k_mix<<<2048, 256, 0, stream>>>(attn1, wpm, bp, x, out);
}

// Round 14
// 257.208 us; speedup vs baseline: 1.2565x; 1.2565x over previous
//
#include <hip/hip_runtime.h>
#include <hip/hip_fp16.h>

#define HW 65536
#define PW 256        // plane width
#define C7SD 85       // conv7 LDS row stride in DWORDS (odd -> 64 lanes hit 32 banks)

// Fast exact-gelu: erf via Abramowitz-Stegun 7.1.26 (|err| <= 1.5e-7).
__device__ __forceinline__ float gelu_f(float v) {
    float ax = fabsf(v) * 0.7071067811865476f;
    float t  = 1.0f / (1.0f + 0.3275911f * ax);
    float p  = t * (0.254829592f + t * (-0.284496736f + t * (1.421413741f
             + t * (-1.453152027f + t * 1.061405429f))));
    float e  = 1.0f - p * __expf(-ax * ax);
    e = copysignf(e, v);
    return 0.5f * v * (1.0f + e);
}

__device__ __forceinline__ unsigned pack2h(float a, float b) {
    __half2 h = __floats2half2_rn(a, b);
    return *reinterpret_cast<unsigned*>(&h);
}

__device__ __forceinline__ void unpack8(uint4 u, float* dst) {
    float2 f;
    f = __half22float2(*reinterpret_cast<__half2*>(&u.x)); dst[0] = f.x; dst[1] = f.y;
    f = __half22float2(*reinterpret_cast<__half2*>(&u.y)); dst[2] = f.x; dst[3] = f.y;
    f = __half22float2(*reinterpret_cast<__half2*>(&u.z)); dst[4] = f.x; dst[5] = f.y;
    f = __half22float2(*reinterpret_cast<__half2*>(&u.w)); dst[6] = f.x; dst[7] = f.y;
}

__device__ __forceinline__ float sgpr_f(float v) {
    union { float f; int i; } u;
    u.f = v;
    u.i = __builtin_amdgcn_readfirstlane(u.i);
    return u.f;
}

// acc(f32) += w(f32) * f16-half of h2 (packed u32), via v_fma_mix_f32 op_sel.
__device__ __forceinline__ void fma_mix_h(float& acc, float w, unsigned h2, int sel) {
    if (sel == 0)
        asm("v_fma_mix_f32 %0, %1, %2, %0 op_sel:[0,0,0] op_sel_hi:[0,1,0]"
            : "+v"(acc) : "v"(w), "v"(h2));
    else
        asm("v_fma_mix_f32 %0, %1, %2, %0 op_sel:[0,1,0] op_sel_hi:[0,1,0]"
            : "+v"(acc) : "v"(w), "v"(h2));
}

// ---------------- K0: pool x over H,W (partial sums, 4 blocks per plane) ------
__global__ __launch_bounds__(256) void k_pool_x(const float* __restrict__ x,
                                                float* __restrict__ partial) {
    __shared__ float red[256];
    const int t = threadIdx.x;
    const int blk = blockIdx.x;              // plane*4 + quarter
    const float* p = x + (size_t)blk * 16384;
    float s = 0.f;
    #pragma unroll
    for (int i = 0; i < 16; ++i) {
        float4 v = *reinterpret_cast<const float4*>(p + (i * 256 + t) * 4);
        s += v.x + v.y + v.z + v.w;
    }
    red[t] = s;
    __syncthreads();
    for (int off = 128; off > 0; off >>= 1) {
        if (t < off) red[t] += red[t + off];
        __syncthreads();
    }
    if (t == 0) partial[blk] = red[0];
}

// Fused per-block routing: partial[(b*64+i)*4+q] -> pooled -> sigmoid(r) ->
// mixed weights for THIS block's plane, left in w_s[taps]. Same reduction
// order as the old k_route_mix (numerics identical).
__device__ __forceinline__ void route_block(const float* __restrict__ partial,
                                            const float* __restrict__ rw,
                                            const float* __restrict__ rb,
                                            const float* __restrict__ wexp,
                                            int b, int c, int taps, int t,
                                            float* pool_s, float* r_s, float* w_s) {
    if (t < 64) {
        float s = 0.f;
        #pragma unroll
        for (int q = 0; q < 4; ++q) s += partial[(b * 64 + t) * 4 + q];
        pool_s[t] = s * (1.0f / 65536.0f);
    }
    __syncthreads();
    if (t < 3) {
        float z = rb[t];
        #pragma unroll
        for (int i = 0; i < 64; ++i) z += pool_s[i] * rw[t * 64 + i];
        r_s[t] = 1.0f / (1.0f + expf(-z));
    }
    __syncthreads();
    if (t < taps) {
        w_s[t] = r_s[0] * wexp[(0 * 64 + c) * taps + t] +
                 r_s[1] * wexp[(1 * 64 + c) * taps + t] +
                 r_s[2] * wexp[(2 * 64 + c) * taps + t];
    }
    __syncthreads();
}

// -------- K2: depthwise 5x5 pad2 + bias + gelu -> fp16, with tile sums --------
// R7 structure (global float4 loads, 8x8/thread, fast gelu) + fused routing.
__global__ __launch_bounds__(256) void k_conv5(const float* __restrict__ x,
                                               const float* __restrict__ partial,
                                               const float* __restrict__ rw,
                                               const float* __restrict__ rb,
                                               const float* __restrict__ wexp,
                                               const float* __restrict__ bias,
                                               __half* __restrict__ attn0,
                                               float* __restrict__ tilesum) {
    __shared__ float red[256];
    __shared__ float pool_s[64];
    __shared__ float r_s[3];
    __shared__ float w_s[25];
    const int blk = blockIdx.x;              // plane*4 + tile (128x128 tiles)
    const int plane = blk >> 2;
    const int tile = blk & 3;
    const int b = plane >> 6;
    const int c = plane & 63;
    const int oy0 = (tile >> 1) << 7;
    const int ox0 = (tile & 1) << 7;
    const int t = threadIdx.x;
    const int ox = ox0 + ((t & 15) << 3);    // 8-wide strip
    const int oy = oy0 + ((t >> 4) << 3);    // 8-tall
    const float* xp = x + (size_t)plane * HW;

    route_block(partial, rw, rb, wexp, b, c, 25, t, pool_s, r_s, w_s);
    float w[25];
    #pragma unroll
    for (int i = 0; i < 25; ++i) w[i] = sgpr_f(w_s[i]);

    float acc[8][8];
    #pragma unroll
    for (int i = 0; i < 8; ++i)
        #pragma unroll
        for (int j = 0; j < 8; ++j) acc[i][j] = 0.f;

    #pragma unroll
    for (int r = 0; r < 12; ++r) {
        const int gy = oy - 2 + r;
        if (gy >= 0 && gy < 256) {
            const float* rp = xp + gy * PW + ox;
            float buf[16];
            float4 v;
            if (ox > 0) v = *reinterpret_cast<const float4*>(rp - 4);
            else        v = make_float4(0.f, 0.f, 0.f, 0.f);
            buf[0] = v.x; buf[1] = v.y; buf[2] = v.z; buf[3] = v.w;
            v = *reinterpret_cast<const float4*>(rp);
            buf[4] = v.x; buf[5] = v.y; buf[6] = v.z; buf[7] = v.w;
            v = *reinterpret_cast<const float4*>(rp + 4);
            buf[8] = v.x; buf[9] = v.y; buf[10] = v.z; buf[11] = v.w;
            if (ox < 248) v = *reinterpret_cast<const float4*>(rp + 8);
            else          v = make_float4(0.f, 0.f, 0.f, 0.f);
            buf[12] = v.x; buf[13] = v.y; buf[14] = v.z; buf[15] = v.w;
            #pragma unroll
            for (int i = 0; i < 8; ++i) {
                const int d = r - i;
                if (d >= 0 && d <= 4) {
                    #pragma unroll
                    for (int dx = 0; dx < 5; ++dx) {
                        const float wv = w[d * 5 + dx];
                        #pragma unroll
                        for (int j = 0; j < 8; ++j)
                            acc[i][j] += wv * buf[j + dx + 2];
                    }
                }
            }
        }
    }
    const float bs = bias[c];
    float lsum = 0.f;
    __half* op = attn0 + (size_t)plane * HW;
    #pragma unroll
    for (int i = 0; i < 8; ++i) {
        float g[8];
        #pragma unroll
        for (int j = 0; j < 8; ++j) {
            g[j] = gelu_f(acc[i][j] + bs);
            lsum += g[j];
        }
        uint4 st;
        st.x = pack2h(g[0], g[1]); st.y = pack2h(g[2], g[3]);
        st.z = pack2h(g[4], g[5]); st.w = pack2h(g[6], g[7]);
        *reinterpret_cast<uint4*>(op + (oy + i) * PW + ox) = st;
    }
    red[t] = lsum;
    __syncthreads();
    for (int off = 128; off > 0; off >>= 1) {
        if (t < off) red[t] += red[t + off];
        __syncthreads();
    }
    if (t == 0) tilesum[blk] = red[0];
}

// -------- K4: depthwise 7x7 dil3 pad9 + bias + gelu, fp16 -> fp16 -------------
// R12 structure (odd-dword-stride LDS, b32 reads, fma_mix; 89.5us best) +
// fused routing from conv5's tilesum.
__global__ __launch_bounds__(256) void k_conv7(const __half* __restrict__ a0,
                                               const float* __restrict__ tilesum,
                                               const float* __restrict__ rw,
                                               const float* __restrict__ rb,
                                               const float* __restrict__ wexp,
                                               const float* __restrict__ bias,
                                               __half* __restrict__ attn1) {
    __shared__ unsigned lds[82 * C7SD];      // 27880 B
    __shared__ float pool_s[64];
    __shared__ float r_s[3];
    __shared__ float w_s[49];
    const int blk = blockIdx.x;              // plane*8 + tile (64-row x 128-col)
    const int plane = blk >> 3;
    const int tile = blk & 7;
    const int b = plane >> 6;
    const int c = plane & 63;
    const int oy0 = (tile >> 1) << 6;        // 0,64,128,192
    const int ox0 = (tile & 1) << 7;         // 0,128
    const int t = threadIdx.x;
    const __half* ap = a0 + (size_t)plane * HW;

    const uint4 z4 = make_uint4(0u, 0u, 0u, 0u);
    #pragma unroll
    for (int it = 0; it < 7; ++it) {
        const int idx = it * 256 + t;
        if (idx < 1722) {                    // 82*21
            const int lr = idx / 21;
            const int c8 = idx - lr * 21;
            const int gy = oy0 - 9 + lr;
            const int gx = ox0 - 16 + (c8 << 3);
            uint4 v = z4;
            if ((unsigned)gy < 256u && (unsigned)gx < 256u)
                v = *reinterpret_cast<const uint4*>(ap + gy * PW + gx);
            unsigned* wp = &lds[lr * C7SD + (c8 << 2)];
            wp[0] = v.x; wp[1] = v.y; wp[2] = v.z; wp[3] = v.w;
        }
    }

    route_block(tilesum, rw, rb, wexp, b, c, 49, t, pool_s, r_s, w_s);
    float w[49];
    #pragma unroll
    for (int i = 0; i < 49; ++i) w[i] = sgpr_f(w_s[i]);
    __syncthreads();                         // staging complete too

    const int tx = t & 3, ty = t >> 2;       // 4 x 64
    const int ox = tx << 5;                  // 32-wide strip: 0,32,64,96
    float acc[32];
    #pragma unroll
    for (int j = 0; j < 32; ++j) acc[j] = 0.f;

    #pragma unroll
    for (int dyi = 0; dyi < 7; ++dyi) {
        const int lr = ty + 3 * dyi;         // 0..81
        const unsigned* lp = &lds[lr * C7SD + (tx << 4)];  // dw base = ox/2
        unsigned hbuf[32];                   // 64 halves: lds cols ox..ox+63
        #pragma unroll
        for (int i = 0; i < 32; ++i) hbuf[i] = lp[i];
        #pragma unroll
        for (int dxi = 0; dxi < 7; ++dxi) {
            const float wv = w[dyi * 7 + dxi];
            const int o = 7 + 3 * dxi;       // half offset for j=0
            #pragma unroll
            for (int j = 0; j < 32; ++j) {
                const int h = o + j;         // compile-time after unroll
                fma_mix_h(acc[j], wv, hbuf[h >> 1], h & 1);
            }
        }
    }

    const float bs = bias[c];
    __half* op = attn1 + (size_t)plane * HW + (size_t)(oy0 + ty) * PW + ox0 + ox;
    #pragma unroll
    for (int q = 0; q < 4; ++q) {
        float g[8];
        #pragma unroll
        for (int j = 0; j < 8; ++j) g[j] = gelu_f(acc[q * 8 + j] + bs);
        uint4 st;
        st.x = pack2h(g[0], g[1]); st.y = pack2h(g[2], g[3]);
        st.z = pack2h(g[4], g[5]); st.w = pack2h(g[6], g[7]);
        *reinterpret_cast<uint4*>(op + (q << 3)) = st;
    }
}

// -------- K5: 1x1 channel mix + bias, then out = x * attn ---------------------
__global__ __launch_bounds__(256) void k_mix(const __half* __restrict__ attn1,
                                             const float* __restrict__ wpm,
                                             const float* __restrict__ bp,
                                             const float* __restrict__ x,
                                             float* __restrict__ out) {
    __shared__ __half A_s[64][256];
    __shared__ float wpT[64][64];
    const int t = threadIdx.x;
    const int blk = blockIdx.x;
    const int b = blk >> 8;
    const int p0g = (blk & 255) << 8;        // 256-pixel chunk
    #pragma unroll
    for (int it = 0; it < 8; ++it) {
        const int ci = it * 256 + t;
        const int row = ci >> 5;
        const int off = (ci & 31) << 3;
        uint4 u = *reinterpret_cast<const uint4*>(attn1 + (size_t)(b * 64 + row) * HW + p0g + off);
        *reinterpret_cast<uint4*>(&A_s[row][off]) = u;
    }
    #pragma unroll
    for (int j = 0; j < 16; ++j) {
        const int idx = j * 256 + t;
        const int cc = idx & 63;
        const int oo = idx >> 6;
        wpT[cc][oo] = wpm[oo * 64 + cc];     // coalesced read, conflicted write (once)
    }
    __syncthreads();
    const int o0 = (t >> 5) << 3;
    const int p0 = (t & 31) << 3;
    float acc[8][8];
    #pragma unroll
    for (int i = 0; i < 8; ++i)
        #pragma unroll
        for (int j = 0; j < 8; ++j) acc[i][j] = 0.f;
    #pragma unroll 4
    for (int cc = 0; cc < 64; ++cc) {
        float4 wa = *reinterpret_cast<const float4*>(&wpT[cc][o0]);
        float4 wb = *reinterpret_cast<const float4*>(&wpT[cc][o0 + 4]);
        const float wv[8] = {wa.x, wa.y, wa.z, wa.w, wb.x, wb.y, wb.z, wb.w};
        float af[8];
        uint4 u = *reinterpret_cast<const uint4*>(&A_s[cc][p0]);
        unpack8(u, af);
        #pragma unroll
        for (int oo = 0; oo < 8; ++oo) {
            const float wvv = wv[oo];
            #pragma unroll
            for (int pp = 0; pp < 8; ++pp) acc[oo][pp] += wvv * af[pp];
        }
    }
    #pragma unroll
    for (int oo = 0; oo < 8; ++oo) {
        const int o = o0 + oo;
        const float bb = bp[o];
        const size_t base = (size_t)(b * 64 + o) * HW + p0g + p0;
        float4 x0 = *reinterpret_cast<const float4*>(x + base);
        float4 x1 = *reinterpret_cast<const float4*>(x + base + 4);
        float4 r0, r1;
        r0.x = x0.x * (acc[oo][0] + bb); r0.y = x0.y * (acc[oo][1] + bb);
        r0.z = x0.z * (acc[oo][2] + bb); r0.w = x0.w * (acc[oo][3] + bb);
        r1.x = x1.x * (acc[oo][4] + bb); r1.y = x1.y * (acc[oo][5] + bb);
        r1.z = x1.z * (acc[oo][6] + bb); r1.w = x1.w * (acc[oo][7] + bb);
        *reinterpret_cast<float4*>(out + base) = r0;
        *reinterpret_cast<float4*>(out + base + 4) = r1;
    }
}

extern "C" void kernel_launch(void* const* d_in, const int* in_sizes, int n_in,
                              void* d_out, int out_size, void* d_ws, size_t ws_size,
                              hipStream_t stream) {
    const float* x   = (const float*)d_in[0];
    const float* w0  = (const float*)d_in[1];
    const float* b0  = (const float*)d_in[2];
    const float* r0w = (const float*)d_in[3];
    const float* r0b = (const float*)d_in[4];
    const float* w1  = (const float*)d_in[5];
    const float* b1  = (const float*)d_in[6];
    const float* r1w = (const float*)d_in[7];
    const float* r1b = (const float*)d_in[8];
    const float* wpm = (const float*)d_in[9];
    const float* bp  = (const float*)d_in[10];
    float* out = (float*)d_out;

    // workspace layout (needs ~134.3 MB)
    char* ws = (char*)d_ws;
    __half* attn0   = (__half*)(ws);                       // 64 MB
    __half* attn1   = (__half*)(ws + 67108864);            // 64 MB
    float* partial0 = (float*)(ws + 134217728);            // 2048 f32
    float* tilesum1 = (float*)(ws + 134217728 + 8192);     // 2048 f32

    k_pool_x<<<2048, 256, 0, stream>>>(x, partial0);
    k_conv5<<<2048, 256, 0, stream>>>(x, partial0, r0w, r0b, w0, b0, attn0, tilesum1);
    k_conv7<<<4096, 256, 0, stream>>>(attn0, tilesum1, r1w, r1b, w1, b1, attn1);
    k_mix<<<2048, 256, 0, stream>>>(attn1, wpm, bp, x, out);
}

// Round 15
// 240.377 us; speedup vs baseline: 1.3444x; 1.0700x over previous
//
#include <hip/hip_runtime.h>
#include <hip/hip_fp16.h>

#define HW 65536
#define PW 256        // plane width
#define C7SD 85       // conv7 LDS row stride in DWORDS (odd -> 64 lanes hit 32 banks)

// Fast exact-gelu: erf via Abramowitz-Stegun 7.1.26 (|err| <= 1.5e-7).
__device__ __forceinline__ float gelu_f(float v) {
    float ax = fabsf(v) * 0.7071067811865476f;
    float t  = 1.0f / (1.0f + 0.3275911f * ax);
    float p  = t * (0.254829592f + t * (-0.284496736f + t * (1.421413741f
             + t * (-1.453152027f + t * 1.061405429f))));
    float e  = 1.0f - p * __expf(-ax * ax);
    e = copysignf(e, v);
    return 0.5f * v * (1.0f + e);
}

__device__ __forceinline__ unsigned pack2h(float a, float b) {
    __half2 h = __floats2half2_rn(a, b);
    return *reinterpret_cast<unsigned*>(&h);
}

__device__ __forceinline__ void unpack8(uint4 u, float* dst) {
    float2 f;
    f = __half22float2(*reinterpret_cast<__half2*>(&u.x)); dst[0] = f.x; dst[1] = f.y;
    f = __half22float2(*reinterpret_cast<__half2*>(&u.y)); dst[2] = f.x; dst[3] = f.y;
    f = __half22float2(*reinterpret_cast<__half2*>(&u.z)); dst[4] = f.x; dst[5] = f.y;
    f = __half22float2(*reinterpret_cast<__half2*>(&u.w)); dst[6] = f.x; dst[7] = f.y;
}

__device__ __forceinline__ float sgpr_f(float v) {
    union { float f; int i; } u;
    u.f = v;
    u.i = __builtin_amdgcn_readfirstlane(u.i);
    return u.f;
}

// acc(f32) += w(f32) * f16-half of h2 (packed u32), via v_fma_mix_f32 op_sel.
__device__ __forceinline__ void fma_mix_h(float& acc, float w, unsigned h2, int sel) {
    if (sel == 0)
        asm("v_fma_mix_f32 %0, %1, %2, %0 op_sel:[0,0,0] op_sel_hi:[0,1,0]"
            : "+v"(acc) : "v"(w), "v"(h2));
    else
        asm("v_fma_mix_f32 %0, %1, %2, %0 op_sel:[0,1,0] op_sel_hi:[0,1,0]"
            : "+v"(acc) : "v"(w), "v"(h2));
}

// acc(f32) += wpk.lo * pr.lo + wpk.hi * pr.hi  (f16 x f16 -> f32 accumulate)
__device__ __forceinline__ void dot2_h(float& acc, unsigned wpk, unsigned pr) {
    asm("v_dot2_f32_f16 %0, %1, %2, %0" : "+v"(acc) : "s"(wpk), "v"(pr));
}

// ---------------- K0: pool x over H,W (partial sums, 4 blocks per plane) ------
__global__ __launch_bounds__(256) void k_pool_x(const float* __restrict__ x,
                                                float* __restrict__ partial) {
    __shared__ float red[256];
    const int t = threadIdx.x;
    const int blk = blockIdx.x;              // plane*4 + quarter
    const float* p = x + (size_t)blk * 16384;
    float s = 0.f;
    #pragma unroll
    for (int i = 0; i < 16; ++i) {
        float4 v = *reinterpret_cast<const float4*>(p + (i * 256 + t) * 4);
        s += v.x + v.y + v.z + v.w;
    }
    red[t] = s;
    __syncthreads();
    for (int off = 128; off > 0; off >>= 1) {
        if (t < off) red[t] += red[t + off];
        __syncthreads();
    }
    if (t == 0) partial[blk] = red[0];
}

// Fused per-block routing (same reduction order as standalone k_route_mix).
__device__ __forceinline__ void route_block(const float* __restrict__ partial,
                                            const float* __restrict__ rw,
                                            const float* __restrict__ rb,
                                            const float* __restrict__ wexp,
                                            int b, int c, int taps, int t,
                                            float* pool_s, float* r_s, float* w_s) {
    if (t < 64) {
        float s = 0.f;
        #pragma unroll
        for (int q = 0; q < 4; ++q) s += partial[(b * 64 + t) * 4 + q];
        pool_s[t] = s * (1.0f / 65536.0f);
    }
    __syncthreads();
    if (t < 3) {
        float z = rb[t];
        #pragma unroll
        for (int i = 0; i < 64; ++i) z += pool_s[i] * rw[t * 64 + i];
        r_s[t] = 1.0f / (1.0f + expf(-z));
    }
    __syncthreads();
    if (t < taps) {
        w_s[t] = r_s[0] * wexp[(0 * 64 + c) * taps + t] +
                 r_s[1] * wexp[(1 * 64 + c) * taps + t] +
                 r_s[2] * wexp[(2 * 64 + c) * taps + t];
    }
    __syncthreads();
}

// -------- K2: depthwise 5x5 pad2 + bias + gelu -> fp16, with tile sums --------
// (R14 version: global float4 loads, 8x8/thread, fused routing — unchanged)
__global__ __launch_bounds__(256) void k_conv5(const float* __restrict__ x,
                                               const float* __restrict__ partial,
                                               const float* __restrict__ rw,
                                               const float* __restrict__ rb,
                                               const float* __restrict__ wexp,
                                               const float* __restrict__ bias,
                                               __half* __restrict__ attn0,
                                               float* __restrict__ tilesum) {
    __shared__ float red[256];
    __shared__ float pool_s[64];
    __shared__ float r_s[3];
    __shared__ float w_s[25];
    const int blk = blockIdx.x;              // plane*4 + tile (128x128 tiles)
    const int plane = blk >> 2;
    const int tile = blk & 3;
    const int b = plane >> 6;
    const int c = plane & 63;
    const int oy0 = (tile >> 1) << 7;
    const int ox0 = (tile & 1) << 7;
    const int t = threadIdx.x;
    const int ox = ox0 + ((t & 15) << 3);    // 8-wide strip
    const int oy = oy0 + ((t >> 4) << 3);    // 8-tall
    const float* xp = x + (size_t)plane * HW;

    route_block(partial, rw, rb, wexp, b, c, 25, t, pool_s, r_s, w_s);
    float w[25];
    #pragma unroll
    for (int i = 0; i < 25; ++i) w[i] = sgpr_f(w_s[i]);

    float acc[8][8];
    #pragma unroll
    for (int i = 0; i < 8; ++i)
        #pragma unroll
        for (int j = 0; j < 8; ++j) acc[i][j] = 0.f;

    #pragma unroll
    for (int r = 0; r < 12; ++r) {
        const int gy = oy - 2 + r;
        if (gy >= 0 && gy < 256) {
            const float* rp = xp + gy * PW + ox;
            float buf[16];
            float4 v;
            if (ox > 0) v = *reinterpret_cast<const float4*>(rp - 4);
            else        v = make_float4(0.f, 0.f, 0.f, 0.f);
            buf[0] = v.x; buf[1] = v.y; buf[2] = v.z; buf[3] = v.w;
            v = *reinterpret_cast<const float4*>(rp);
            buf[4] = v.x; buf[5] = v.y; buf[6] = v.z; buf[7] = v.w;
            v = *reinterpret_cast<const float4*>(rp + 4);
            buf[8] = v.x; buf[9] = v.y; buf[10] = v.z; buf[11] = v.w;
            if (ox < 248) v = *reinterpret_cast<const float4*>(rp + 8);
            else          v = make_float4(0.f, 0.f, 0.f, 0.f);
            buf[12] = v.x; buf[13] = v.y; buf[14] = v.z; buf[15] = v.w;
            #pragma unroll
            for (int i = 0; i < 8; ++i) {
                const int d = r - i;
                if (d >= 0 && d <= 4) {
                    #pragma unroll
                    for (int dx = 0; dx < 5; ++dx) {
                        const float wv = w[d * 5 + dx];
                        #pragma unroll
                        for (int j = 0; j < 8; ++j)
                            acc[i][j] += wv * buf[j + dx + 2];
                    }
                }
            }
        }
    }
    const float bs = bias[c];
    float lsum = 0.f;
    __half* op = attn0 + (size_t)plane * HW;
    #pragma unroll
    for (int i = 0; i < 8; ++i) {
        float g[8];
        #pragma unroll
        for (int j = 0; j < 8; ++j) {
            g[j] = gelu_f(acc[i][j] + bs);
            lsum += g[j];
        }
        uint4 st;
        st.x = pack2h(g[0], g[1]); st.y = pack2h(g[2], g[3]);
        st.z = pack2h(g[4], g[5]); st.w = pack2h(g[6], g[7]);
        *reinterpret_cast<uint4*>(op + (oy + i) * PW + ox) = st;
    }
    red[t] = lsum;
    __syncthreads();
    for (int off = 128; off > 0; off >>= 1) {
        if (t < off) red[t] += red[t + off];
        __syncthreads();
    }
    if (t == 0) tilesum[blk] = red[0];
}

// -------- K4: depthwise 7x7 dil3 pad9 + bias + gelu, fp16 -> fp16 -------------
// R12 shell + v_dot2_f32_f16 row-pairing: rows (dyi,dyi+1) share columns, so
// one v_perm per column builds the (rowA,rowB) f16 pair consumed by all 7 dxi
// taps -> 2 taps/instruction with f32 accumulation. Main loop 1270 vs 1792
// instr (-29%). Tail dyi=6 stays fma_mix. Conv times scale with instr count
// (R14 cross-kernel fit), so predicted ~-20%.
__global__ __launch_bounds__(256, 3) void k_conv7(const __half* __restrict__ a0,
                                                  const float* __restrict__ tilesum,
                                                  const float* __restrict__ rw,
                                                  const float* __restrict__ rb,
                                                  const float* __restrict__ wexp,
                                                  const float* __restrict__ bias,
                                                  __half* __restrict__ attn1) {
    __shared__ unsigned lds[82 * C7SD];      // 27880 B
    __shared__ float pool_s[64];
    __shared__ float r_s[3];
    __shared__ float w_s[49];
    const int blk = blockIdx.x;              // plane*8 + tile (64-row x 128-col)
    const int plane = blk >> 3;
    const int tile = blk & 7;
    const int b = plane >> 6;
    const int c = plane & 63;
    const int oy0 = (tile >> 1) << 6;        // 0,64,128,192
    const int ox0 = (tile & 1) << 7;         // 0,128
    const int t = threadIdx.x;
    const __half* ap = a0 + (size_t)plane * HW;

    const uint4 z4 = make_uint4(0u, 0u, 0u, 0u);
    #pragma unroll
    for (int it = 0; it < 7; ++it) {
        const int idx = it * 256 + t;
        if (idx < 1722) {                    // 82*21
            const int lr = idx / 21;
            const int c8 = idx - lr * 21;
            const int gy = oy0 - 9 + lr;
            const int gx = ox0 - 16 + (c8 << 3);
            uint4 v = z4;
            if ((unsigned)gy < 256u && (unsigned)gx < 256u)
                v = *reinterpret_cast<const uint4*>(ap + gy * PW + gx);
            unsigned* wp = &lds[lr * C7SD + (c8 << 2)];
            wp[0] = v.x; wp[1] = v.y; wp[2] = v.z; wp[3] = v.w;
        }
    }

    route_block(tilesum, rw, rb, wexp, b, c, 49, t, pool_s, r_s, w_s);
    // weight row-pairs (dyi,dyi+1) packed f16x2 -> SGPRs; tail dyi=6 scalar.
    unsigned wpk[21];
    #pragma unroll
    for (int p = 0; p < 3; ++p)
        #pragma unroll
        for (int dxi = 0; dxi < 7; ++dxi)
            wpk[p * 7 + dxi] = (unsigned)__builtin_amdgcn_readfirstlane(
                (int)pack2h(w_s[(2 * p) * 7 + dxi], w_s[(2 * p + 1) * 7 + dxi]));
    float wt[7];
    #pragma unroll
    for (int i = 0; i < 7; ++i) wt[i] = sgpr_f(w_s[42 + i]);
    __syncthreads();                         // staging complete too

    const int tx = t & 3, ty = t >> 2;       // 4 x 64
    const int ox = tx << 5;                  // 32-wide strip: 0,32,64,96
    float acc[32];
    #pragma unroll
    for (int j = 0; j < 32; ++j) acc[j] = 0.f;

    // row-pair bodies: dyi = 2p, 2p+1
    #pragma unroll
    for (int p = 0; p < 3; ++p) {
        const int rA = ty + 6 * p;           // lr of dyi=2p   (<= 63+12 = 75)
        const unsigned* lA = &lds[rA * C7SD + (tx << 4)];
        const unsigned* lB = &lds[(rA + 3) * C7SD + (tx << 4)];
        unsigned hA[32], hB[32];
        #pragma unroll
        for (int i = 0; i < 32; ++i) hA[i] = lA[i];
        #pragma unroll
        for (int i = 0; i < 32; ++i) hB[i] = lB[i];
        unsigned pr[50];                     // pair (rowA[s], rowB[s]), s = i+7
        #pragma unroll
        for (int i = 0; i < 50; ++i) {
            const int s = i + 7, k = s >> 1;
            pr[i] = __builtin_amdgcn_perm(hB[k], hA[k],
                                          (s & 1) ? 0x07060302u : 0x05040100u);
        }
        #pragma unroll
        for (int dxi = 0; dxi < 7; ++dxi) {
            const unsigned wp = wpk[p * 7 + dxi];
            #pragma unroll
            for (int j = 0; j < 32; ++j)
                dot2_h(acc[j], wp, pr[3 * dxi + j]);
        }
    }
    // tail: dyi = 6
    {
        const unsigned* lp = &lds[(ty + 18) * C7SD + (tx << 4)];
        unsigned hbuf[32];
        #pragma unroll
        for (int i = 0; i < 32; ++i) hbuf[i] = lp[i];
        #pragma unroll
        for (int dxi = 0; dxi < 7; ++dxi) {
            const float wv = wt[dxi];
            const int o = 7 + 3 * dxi;
            #pragma unroll
            for (int j = 0; j < 32; ++j) {
                const int h = o + j;
                fma_mix_h(acc[j], wv, hbuf[h >> 1], h & 1);
            }
        }
    }

    const float bs = bias[c];
    __half* op = attn1 + (size_t)plane * HW + (size_t)(oy0 + ty) * PW + ox0 + ox;
    #pragma unroll
    for (int q = 0; q < 4; ++q) {
        float g[8];
        #pragma unroll
        for (int j = 0; j < 8; ++j) g[j] = gelu_f(acc[q * 8 + j] + bs);
        uint4 st;
        st.x = pack2h(g[0], g[1]); st.y = pack2h(g[2], g[3]);
        st.z = pack2h(g[4], g[5]); st.w = pack2h(g[6], g[7]);
        *reinterpret_cast<uint4*>(op + (q << 3)) = st;
    }
}

// -------- K5: 1x1 channel mix + bias, then out = x * attn ---------------------
__global__ __launch_bounds__(256) void k_mix(const __half* __restrict__ attn1,
                                             const float* __restrict__ wpm,
                                             const float* __restrict__ bp,
                                             const float* __restrict__ x,
                                             float* __restrict__ out) {
    __shared__ __half A_s[64][256];
    __shared__ float wpT[64][64];
    const int t = threadIdx.x;
    const int blk = blockIdx.x;
    const int b = blk >> 8;
    const int p0g = (blk & 255) << 8;        // 256-pixel chunk
    #pragma unroll
    for (int it = 0; it < 8; ++it) {
        const int ci = it * 256 + t;
        const int row = ci >> 5;
        const int off = (ci & 31) << 3;
        uint4 u = *reinterpret_cast<const uint4*>(attn1 + (size_t)(b * 64 + row) * HW + p0g + off);
        *reinterpret_cast<uint4*>(&A_s[row][off]) = u;
    }
    #pragma unroll
    for (int j = 0; j < 16; ++j) {
        const int idx = j * 256 + t;
        const int cc = idx & 63;
        const int oo = idx >> 6;
        wpT[cc][oo] = wpm[oo * 64 + cc];     // coalesced read, conflicted write (once)
    }
    __syncthreads();
    const int o0 = (t >> 5) << 3;
    const int p0 = (t & 31) << 3;
    float acc[8][8];
    #pragma unroll
    for (int i = 0; i < 8; ++i)
        #pragma unroll
        for (int j = 0; j < 8; ++j) acc[i][j] = 0.f;
    #pragma unroll 4
    for (int cc = 0; cc < 64; ++cc) {
        float4 wa = *reinterpret_cast<const float4*>(&wpT[cc][o0]);
        float4 wb = *reinterpret_cast<const float4*>(&wpT[cc][o0 + 4]);
        const float wv[8] = {wa.x, wa.y, wa.z, wa.w, wb.x, wb.y, wb.z, wb.w};
        float af[8];
        uint4 u = *reinterpret_cast<const uint4*>(&A_s[cc][p0]);
        unpack8(u, af);
        #pragma unroll
        for (int oo = 0; oo < 8; ++oo) {
            const float wvv = wv[oo];
            #pragma unroll
            for (int pp = 0; pp < 8; ++pp) acc[oo][pp] += wvv * af[pp];
        }
    }
    #pragma unroll
    for (int oo = 0; oo < 8; ++oo) {
        const int o = o0 + oo;
        const float bb = bp[o];
        const size_t base = (size_t)(b * 64 + o) * HW + p0g + p0;
        float4 x0 = *reinterpret_cast<const float4*>(x + base);
        float4 x1 = *reinterpret_cast<const float4*>(x + base + 4);
        float4 r0, r1;
        r0.x = x0.x * (acc[oo][0] + bb); r0.y = x0.y * (acc[oo][1] + bb);
        r0.z = x0.z * (acc[oo][2] + bb); r0.w = x0.w * (acc[oo][3] + bb);
        r1.x = x1.x * (acc[oo][4] + bb); r1.y = x1.y * (acc[oo][5] + bb);
        r1.z = x1.z * (acc[oo][6] + bb); r1.w = x1.w * (acc[oo][7] + bb);
        *reinterpret_cast<float4*>(out + base) = r0;
        *reinterpret_cast<float4*>(out + base + 4) = r1;
    }
}

extern "C" void kernel_launch(void* const* d_in, const int* in_sizes, int n_in,
                              void* d_out, int out_size, void* d_ws, size_t ws_size,
                              hipStream_t stream) {
    const float* x   = (const float*)d_in[0];
    const float* w0  = (const float*)d_in[1];
    const float* b0  = (const float*)d_in[2];
    const float* r0w = (const float*)d_in[3];
    const float* r0b = (const float*)d_in[4];
    const float* w1  = (const float*)d_in[5];
    const float* b1  = (const float*)d_in[6];
    const float* r1w = (const float*)d_in[7];
    const float* r1b = (const float*)d_in[8];
    const float* wpm = (const float*)d_in[9];
    const float* bp  = (const float*)d_in[10];
    float* out = (float*)d_out;

    // workspace layout (needs ~134.3 MB)
    char* ws = (char*)d_ws;
    __half* attn0   = (__half*)(ws);                       // 64 MB
    __half* attn1   = (__half*)(ws + 67108864);            // 64 MB
    float* partial0 = (float*)(ws + 134217728);            // 2048 f32
    float* tilesum1 = (float*)(ws + 134217728 + 8192);     // 2048 f32

    k_pool_x<<<2048, 256, 0, stream>>>(x, partial0);
    k_conv5<<<2048, 256, 0, stream>>>(x, partial0, r0w, r0b, w0, b0, attn0, tilesum1);
    k_conv7<<<4096, 256, 0, stream>>>(attn0, tilesum1, r1w, r1b, w1, b1, attn1);
    k_mix<<<2048, 256, 0, stream>>>(attn1, wpm, bp, x, out);
}

// Round 16
// 234.628 us; speedup vs baseline: 1.3774x; 1.0245x over previous
//
#include <hip/hip_runtime.h>
#include <hip/hip_fp16.h>

#define HW 65536
#define PW 256        // plane width
#define C7SD 85       // conv7 LDS row stride in DWORDS (odd -> 64 lanes hit 32 banks)

// Fast exact-gelu: erf via Abramowitz-Stegun 7.1.26 (|err| <= 1.5e-7).
__device__ __forceinline__ float gelu_f(float v) {
    float ax = fabsf(v) * 0.7071067811865476f;
    float t  = 1.0f / (1.0f + 0.3275911f * ax);
    float p  = t * (0.254829592f + t * (-0.284496736f + t * (1.421413741f
             + t * (-1.453152027f + t * 1.061405429f))));
    float e  = 1.0f - p * __expf(-ax * ax);
    e = copysignf(e, v);
    return 0.5f * v * (1.0f + e);
}

__device__ __forceinline__ unsigned pack2h(float a, float b) {
    __half2 h = __floats2half2_rn(a, b);
    return *reinterpret_cast<unsigned*>(&h);
}

__device__ __forceinline__ float sgpr_f(float v) {
    union { float f; int i; } u;
    u.f = v;
    u.i = __builtin_amdgcn_readfirstlane(u.i);
    return u.f;
}

// acc(f32) += w(f32) * f16-half of h2 (packed u32), via v_fma_mix_f32 op_sel.
__device__ __forceinline__ void fma_mix_h(float& acc, float w, unsigned h2, int sel) {
    if (sel == 0)
        asm("v_fma_mix_f32 %0, %1, %2, %0 op_sel:[0,0,0] op_sel_hi:[0,1,0]"
            : "+v"(acc) : "v"(w), "v"(h2));
    else
        asm("v_fma_mix_f32 %0, %1, %2, %0 op_sel:[0,1,0] op_sel_hi:[0,1,0]"
            : "+v"(acc) : "v"(w), "v"(h2));
}

// acc(f32) += wpk.lo*pr.lo + wpk.hi*pr.hi (f16 pairs, f32 accumulate)
__device__ __forceinline__ void dot2_h(float& acc, unsigned wpk, unsigned pr) {
    asm("v_dot2_f32_f16 %0, %1, %2, %0" : "+v"(acc) : "s"(wpk), "v"(pr));
}
__device__ __forceinline__ void dot2_hv(float& acc, unsigned wpk, unsigned pr) {
    asm("v_dot2_f32_f16 %0, %1, %2, %0" : "+v"(acc) : "v"(wpk), "v"(pr));
}

// ---------------- K0: pool x over H,W (partial sums, 4 blocks per plane) ------
__global__ __launch_bounds__(256) void k_pool_x(const float* __restrict__ x,
                                                float* __restrict__ partial) {
    __shared__ float red[256];
    const int t = threadIdx.x;
    const int blk = blockIdx.x;              // plane*4 + quarter
    const float* p = x + (size_t)blk * 16384;
    float s = 0.f;
    #pragma unroll
    for (int i = 0; i < 16; ++i) {
        float4 v = *reinterpret_cast<const float4*>(p + (i * 256 + t) * 4);
        s += v.x + v.y + v.z + v.w;
    }
    red[t] = s;
    __syncthreads();
    for (int off = 128; off > 0; off >>= 1) {
        if (t < off) red[t] += red[t + off];
        __syncthreads();
    }
    if (t == 0) partial[blk] = red[0];
}

// Fused per-block routing (same reduction order as standalone k_route_mix).
__device__ __forceinline__ void route_block(const float* __restrict__ partial,
                                            const float* __restrict__ rw,
                                            const float* __restrict__ rb,
                                            const float* __restrict__ wexp,
                                            int b, int c, int taps, int t,
                                            float* pool_s, float* r_s, float* w_s) {
    if (t < 64) {
        float s = 0.f;
        #pragma unroll
        for (int q = 0; q < 4; ++q) s += partial[(b * 64 + t) * 4 + q];
        pool_s[t] = s * (1.0f / 65536.0f);
    }
    __syncthreads();
    if (t < 3) {
        float z = rb[t];
        #pragma unroll
        for (int i = 0; i < 64; ++i) z += pool_s[i] * rw[t * 64 + i];
        r_s[t] = 1.0f / (1.0f + expf(-z));
    }
    __syncthreads();
    if (t < taps) {
        w_s[t] = r_s[0] * wexp[(0 * 64 + c) * taps + t] +
                 r_s[1] * wexp[(1 * 64 + c) * taps + t] +
                 r_s[2] * wexp[(2 * 64 + c) * taps + t];
    }
    __syncthreads();
}

// -------- K2: depthwise 5x5 pad2 + bias + gelu -> fp16, with tile sums --------
// (R14 version: global float4 loads, 8x8/thread, fused routing — unchanged)
__global__ __launch_bounds__(256) void k_conv5(const float* __restrict__ x,
                                               const float* __restrict__ partial,
                                               const float* __restrict__ rw,
                                               const float* __restrict__ rb,
                                               const float* __restrict__ wexp,
                                               const float* __restrict__ bias,
                                               __half* __restrict__ attn0,
                                               float* __restrict__ tilesum) {
    __shared__ float red[256];
    __shared__ float pool_s[64];
    __shared__ float r_s[3];
    __shared__ float w_s[25];
    const int blk = blockIdx.x;              // plane*4 + tile (128x128 tiles)
    const int plane = blk >> 2;
    const int tile = blk & 3;
    const int b = plane >> 6;
    const int c = plane & 63;
    const int oy0 = (tile >> 1) << 7;
    const int ox0 = (tile & 1) << 7;
    const int t = threadIdx.x;
    const int ox = ox0 + ((t & 15) << 3);    // 8-wide strip
    const int oy = oy0 + ((t >> 4) << 3);    // 8-tall
    const float* xp = x + (size_t)plane * HW;

    route_block(partial, rw, rb, wexp, b, c, 25, t, pool_s, r_s, w_s);
    float w[25];
    #pragma unroll
    for (int i = 0; i < 25; ++i) w[i] = sgpr_f(w_s[i]);

    float acc[8][8];
    #pragma unroll
    for (int i = 0; i < 8; ++i)
        #pragma unroll
        for (int j = 0; j < 8; ++j) acc[i][j] = 0.f;

    #pragma unroll
    for (int r = 0; r < 12; ++r) {
        const int gy = oy - 2 + r;
        if (gy >= 0 && gy < 256) {
            const float* rp = xp + gy * PW + ox;
            float buf[16];
            float4 v;
            if (ox > 0) v = *reinterpret_cast<const float4*>(rp - 4);
            else        v = make_float4(0.f, 0.f, 0.f, 0.f);
            buf[0] = v.x; buf[1] = v.y; buf[2] = v.z; buf[3] = v.w;
            v = *reinterpret_cast<const float4*>(rp);
            buf[4] = v.x; buf[5] = v.y; buf[6] = v.z; buf[7] = v.w;
            v = *reinterpret_cast<const float4*>(rp + 4);
            buf[8] = v.x; buf[9] = v.y; buf[10] = v.z; buf[11] = v.w;
            if (ox < 248) v = *reinterpret_cast<const float4*>(rp + 8);
            else          v = make_float4(0.f, 0.f, 0.f, 0.f);
            buf[12] = v.x; buf[13] = v.y; buf[14] = v.z; buf[15] = v.w;
            #pragma unroll
            for (int i = 0; i < 8; ++i) {
                const int d = r - i;
                if (d >= 0 && d <= 4) {
                    #pragma unroll
                    for (int dx = 0; dx < 5; ++dx) {
                        const float wv = w[d * 5 + dx];
                        #pragma unroll
                        for (int j = 0; j < 8; ++j)
                            acc[i][j] += wv * buf[j + dx + 2];
                    }
                }
            }
        }
    }
    const float bs = bias[c];
    float lsum = 0.f;
    __half* op = attn0 + (size_t)plane * HW;
    #pragma unroll
    for (int i = 0; i < 8; ++i) {
        float g[8];
        #pragma unroll
        for (int j = 0; j < 8; ++j) {
            g[j] = gelu_f(acc[i][j] + bs);
            lsum += g[j];
        }
        uint4 st;
        st.x = pack2h(g[0], g[1]); st.y = pack2h(g[2], g[3]);
        st.z = pack2h(g[4], g[5]); st.w = pack2h(g[6], g[7]);
        *reinterpret_cast<uint4*>(op + (oy + i) * PW + ox) = st;
    }
    red[t] = lsum;
    __syncthreads();
    for (int off = 128; off > 0; off >>= 1) {
        if (t < off) red[t] += red[t + off];
        __syncthreads();
    }
    if (t == 0) tilesum[blk] = red[0];
}

// -------- K4: depthwise 7x7 dil3 pad9 + bias + gelu, fp16 -> fp16 -------------
// (R15 version: dot2 row-pairing, odd-stride LDS — unchanged)
__global__ __launch_bounds__(256, 3) void k_conv7(const __half* __restrict__ a0,
                                                  const float* __restrict__ tilesum,
                                                  const float* __restrict__ rw,
                                                  const float* __restrict__ rb,
                                                  const float* __restrict__ wexp,
                                                  const float* __restrict__ bias,
                                                  __half* __restrict__ attn1) {
    __shared__ unsigned lds[82 * C7SD];      // 27880 B
    __shared__ float pool_s[64];
    __shared__ float r_s[3];
    __shared__ float w_s[49];
    const int blk = blockIdx.x;              // plane*8 + tile (64-row x 128-col)
    const int plane = blk >> 3;
    const int tile = blk & 7;
    const int b = plane >> 6;
    const int c = plane & 63;
    const int oy0 = (tile >> 1) << 6;        // 0,64,128,192
    const int ox0 = (tile & 1) << 7;         // 0,128
    const int t = threadIdx.x;
    const __half* ap = a0 + (size_t)plane * HW;

    const uint4 z4 = make_uint4(0u, 0u, 0u, 0u);
    #pragma unroll
    for (int it = 0; it < 7; ++it) {
        const int idx = it * 256 + t;
        if (idx < 1722) {                    // 82*21
            const int lr = idx / 21;
            const int c8 = idx - lr * 21;
            const int gy = oy0 - 9 + lr;
            const int gx = ox0 - 16 + (c8 << 3);
            uint4 v = z4;
            if ((unsigned)gy < 256u && (unsigned)gx < 256u)
                v = *reinterpret_cast<const uint4*>(ap + gy * PW + gx);
            unsigned* wp = &lds[lr * C7SD + (c8 << 2)];
            wp[0] = v.x; wp[1] = v.y; wp[2] = v.z; wp[3] = v.w;
        }
    }

    route_block(tilesum, rw, rb, wexp, b, c, 49, t, pool_s, r_s, w_s);
    unsigned wpk[21];
    #pragma unroll
    for (int p = 0; p < 3; ++p)
        #pragma unroll
        for (int dxi = 0; dxi < 7; ++dxi)
            wpk[p * 7 + dxi] = (unsigned)__builtin_amdgcn_readfirstlane(
                (int)pack2h(w_s[(2 * p) * 7 + dxi], w_s[(2 * p + 1) * 7 + dxi]));
    float wt[7];
    #pragma unroll
    for (int i = 0; i < 7; ++i) wt[i] = sgpr_f(w_s[42 + i]);
    __syncthreads();                         // staging complete too

    const int tx = t & 3, ty = t >> 2;       // 4 x 64
    const int ox = tx << 5;                  // 32-wide strip: 0,32,64,96
    float acc[32];
    #pragma unroll
    for (int j = 0; j < 32; ++j) acc[j] = 0.f;

    #pragma unroll
    for (int p = 0; p < 3; ++p) {
        const int rA = ty + 6 * p;
        const unsigned* lA = &lds[rA * C7SD + (tx << 4)];
        const unsigned* lB = &lds[(rA + 3) * C7SD + (tx << 4)];
        unsigned hA[32], hB[32];
        #pragma unroll
        for (int i = 0; i < 32; ++i) hA[i] = lA[i];
        #pragma unroll
        for (int i = 0; i < 32; ++i) hB[i] = lB[i];
        unsigned pr[50];
        #pragma unroll
        for (int i = 0; i < 50; ++i) {
            const int s = i + 7, k = s >> 1;
            pr[i] = __builtin_amdgcn_perm(hB[k], hA[k],
                                          (s & 1) ? 0x07060302u : 0x05040100u);
        }
        #pragma unroll
        for (int dxi = 0; dxi < 7; ++dxi) {
            const unsigned wp = wpk[p * 7 + dxi];
            #pragma unroll
            for (int j = 0; j < 32; ++j)
                dot2_h(acc[j], wp, pr[3 * dxi + j]);
        }
    }
    {
        const unsigned* lp = &lds[(ty + 18) * C7SD + (tx << 4)];
        unsigned hbuf[32];
        #pragma unroll
        for (int i = 0; i < 32; ++i) hbuf[i] = lp[i];
        #pragma unroll
        for (int dxi = 0; dxi < 7; ++dxi) {
            const float wv = wt[dxi];
            const int o = 7 + 3 * dxi;
            #pragma unroll
            for (int j = 0; j < 32; ++j) {
                const int h = o + j;
                fma_mix_h(acc[j], wv, hbuf[h >> 1], h & 1);
            }
        }
    }

    const float bs = bias[c];
    __half* op = attn1 + (size_t)plane * HW + (size_t)(oy0 + ty) * PW + ox0 + ox;
    #pragma unroll
    for (int q = 0; q < 4; ++q) {
        float g[8];
        #pragma unroll
        for (int j = 0; j < 8; ++j) g[j] = gelu_f(acc[q * 8 + j] + bs);
        uint4 st;
        st.x = pack2h(g[0], g[1]); st.y = pack2h(g[2], g[3]);
        st.z = pack2h(g[4], g[5]); st.w = pack2h(g[6], g[7]);
        *reinterpret_cast<uint4*>(op + (q << 3)) = st;
    }
}

// -------- K5: 1x1 channel mix + bias, then out = x * attn ---------------------
// dot2 channel-pairing (R15 conv7 technique): weights pre-packed f16x2 in LDS
// w2[cpair][o]; one v_perm per (cpair,pixel) builds (a[c],a[c+1]) pair; inner
// loop is 64 v_dot2 per cpair. ~2500 VALU instr/thread vs 4800 scalar-FMA.
__global__ __launch_bounds__(256) void k_mix(const __half* __restrict__ attn1,
                                             const float* __restrict__ wpm,
                                             const float* __restrict__ bp,
                                             const float* __restrict__ x,
                                             float* __restrict__ out) {
    __shared__ __half A_s[64][256];          // 32 KB
    __shared__ unsigned w2_s[32][64];        // 8 KB: (c-pair) x (o), f16x2
    const int t = threadIdx.x;
    const int blk = blockIdx.x;
    const int b = blk >> 8;
    const int p0g = (blk & 255) << 8;        // 256-pixel chunk
    #pragma unroll
    for (int it = 0; it < 8; ++it) {
        const int ci = it * 256 + t;
        const int row = ci >> 5;
        const int off = (ci & 31) << 3;
        uint4 u = *reinterpret_cast<const uint4*>(attn1 + (size_t)(b * 64 + row) * HW + p0g + off);
        *reinterpret_cast<uint4*>(&A_s[row][off]) = u;
    }
    #pragma unroll
    for (int j = 0; j < 8; ++j) {
        const int idx = j * 256 + t;         // 2048 entries
        const int oo = idx >> 5;
        const int cc2 = idx & 31;
        w2_s[cc2][oo] = pack2h(wpm[oo * 64 + 2 * cc2], wpm[oo * 64 + 2 * cc2 + 1]);
    }
    __syncthreads();
    const int o0 = (t >> 5) << 3;
    const int p0 = (t & 31) << 3;
    float acc[8][8];
    #pragma unroll
    for (int i = 0; i < 8; ++i)
        #pragma unroll
        for (int j = 0; j < 8; ++j) acc[i][j] = 0.f;
    #pragma unroll 4
    for (int cc2 = 0; cc2 < 32; ++cc2) {
        uint4 a0 = *reinterpret_cast<const uint4*>(&A_s[2 * cc2][p0]);
        uint4 a1 = *reinterpret_cast<const uint4*>(&A_s[2 * cc2 + 1][p0]);
        const unsigned a0w[4] = {a0.x, a0.y, a0.z, a0.w};
        const unsigned a1w[4] = {a1.x, a1.y, a1.z, a1.w};
        unsigned pr[8];
        #pragma unroll
        for (int j = 0; j < 8; ++j)
            pr[j] = __builtin_amdgcn_perm(a1w[j >> 1], a0w[j >> 1],
                                          (j & 1) ? 0x07060302u : 0x05040100u);
        uint4 wv0 = *reinterpret_cast<const uint4*>(&w2_s[cc2][o0]);
        uint4 wv1 = *reinterpret_cast<const uint4*>(&w2_s[cc2][o0 + 4]);
        const unsigned wv[8] = {wv0.x, wv0.y, wv0.z, wv0.w,
                                wv1.x, wv1.y, wv1.z, wv1.w};
        #pragma unroll
        for (int oo = 0; oo < 8; ++oo) {
            const unsigned wvv = wv[oo];
            #pragma unroll
            for (int pp = 0; pp < 8; ++pp)
                dot2_hv(acc[oo][pp], wvv, pr[pp]);
        }
    }
    #pragma unroll
    for (int oo = 0; oo < 8; ++oo) {
        const int o = o0 + oo;
        const float bb = bp[o];
        const size_t base = (size_t)(b * 64 + o) * HW + p0g + p0;
        float4 x0 = *reinterpret_cast<const float4*>(x + base);
        float4 x1 = *reinterpret_cast<const float4*>(x + base + 4);
        float4 r0, r1;
        r0.x = x0.x * (acc[oo][0] + bb); r0.y = x0.y * (acc[oo][1] + bb);
        r0.z = x0.z * (acc[oo][2] + bb); r0.w = x0.w * (acc[oo][3] + bb);
        r1.x = x1.x * (acc[oo][4] + bb); r1.y = x1.y * (acc[oo][5] + bb);
        r1.z = x1.z * (acc[oo][6] + bb); r1.w = x1.w * (acc[oo][7] + bb);
        *reinterpret_cast<float4*>(out + base) = r0;
        *reinterpret_cast<float4*>(out + base + 4) = r1;
    }
}

extern "C" void kernel_launch(void* const* d_in, const int* in_sizes, int n_in,
                              void* d_out, int out_size, void* d_ws, size_t ws_size,
                              hipStream_t stream) {
    const float* x   = (const float*)d_in[0];
    const float* w0  = (const float*)d_in[1];
    const float* b0  = (const float*)d_in[2];
    const float* r0w = (const float*)d_in[3];
    const float* r0b = (const float*)d_in[4];
    const float* w1  = (const float*)d_in[5];
    const float* b1  = (const float*)d_in[6];
    const float* r1w = (const float*)d_in[7];
    const float* r1b = (const float*)d_in[8];
    const float* wpm = (const float*)d_in[9];
    const float* bp  = (const float*)d_in[10];
    float* out = (float*)d_out;

    // workspace layout (needs ~134.3 MB)
    char* ws = (char*)d_ws;
    __half* attn0   = (__half*)(ws);                       // 64 MB
    __half* attn1   = (__half*)(ws + 67108864);            // 64 MB
    float* partial0 = (float*)(ws + 134217728);            // 2048 f32
    float* tilesum1 = (float*)(ws + 134217728 + 8192);     // 2048 f32

    k_pool_x<<<2048, 256, 0, stream>>>(x, partial0);
    k_conv5<<<2048, 256, 0, stream>>>(x, partial0, r0w, r0b, w0, b0, attn0, tilesum1);
    k_conv7<<<4096, 256, 0, stream>>>(attn0, tilesum1, r1w, r1b, w1, b1, attn1);
    k_mix<<<2048, 256, 0, stream>>>(attn1, wpm, bp, x, out);
}

// Round 18
// 227.745 us; speedup vs baseline: 1.4190x; 1.0302x over previous
//
#include <hip/hip_runtime.h>
#include <hip/hip_fp16.h>

#define HW 65536
#define PW 256        // plane width
#define C7SD 85       // conv7 LDS row stride in DWORDS (odd -> 64 lanes hit 32 banks)

// Fast exact-gelu: erf via Abramowitz-Stegun 7.1.26 (|err| <= 1.5e-7).
__device__ __forceinline__ float gelu_f(float v) {
    float ax = fabsf(v) * 0.7071067811865476f;
    float t  = 1.0f / (1.0f + 0.3275911f * ax);
    float p  = t * (0.254829592f + t * (-0.284496736f + t * (1.421413741f
             + t * (-1.453152027f + t * 1.061405429f))));
    float e  = 1.0f - p * __expf(-ax * ax);
    e = copysignf(e, v);
    return 0.5f * v * (1.0f + e);
}

__device__ __forceinline__ unsigned pack2h(float a, float b) {
    __half2 h = __floats2half2_rn(a, b);
    return *reinterpret_cast<unsigned*>(&h);
}

__device__ __forceinline__ float sgpr_f(float v) {
    union { float f; int i; } u;
    u.f = v;
    u.i = __builtin_amdgcn_readfirstlane(u.i);
    return u.f;
}

// acc(f32) += w(f32) * f16-half of h2 (packed u32), via v_fma_mix_f32 op_sel.
__device__ __forceinline__ void fma_mix_h(float& acc, float w, unsigned h2, int sel) {
    if (sel == 0)
        asm("v_fma_mix_f32 %0, %1, %2, %0 op_sel:[0,0,0] op_sel_hi:[0,1,0]"
            : "+v"(acc) : "v"(w), "v"(h2));
    else
        asm("v_fma_mix_f32 %0, %1, %2, %0 op_sel:[0,1,0] op_sel_hi:[0,1,0]"
            : "+v"(acc) : "v"(w), "v"(h2));
}

// acc(f32) += wpk.lo*pr.lo + wpk.hi*pr.hi (f16 pairs, f32 accumulate)
__device__ __forceinline__ void dot2_h(float& acc, unsigned wpk, unsigned pr) {
    asm("v_dot2_f32_f16 %0, %1, %2, %0" : "+v"(acc) : "s"(wpk), "v"(pr));
}
__device__ __forceinline__ void dot2_hv(float& acc, unsigned wpk, unsigned pr) {
    asm("v_dot2_f32_f16 %0, %1, %2, %0" : "+v"(acc) : "v"(wpk), "v"(pr));
}

// ---------------- K0: pool x over H,W (partial sums, 4 blocks per plane) ------
__global__ __launch_bounds__(256) void k_pool_x(const float* __restrict__ x,
                                                float* __restrict__ partial) {
    __shared__ float red[256];
    const int t = threadIdx.x;
    const int blk = blockIdx.x;              // plane*4 + quarter
    const float* p = x + (size_t)blk * 16384;
    float s = 0.f;
    #pragma unroll
    for (int i = 0; i < 16; ++i) {
        float4 v = *reinterpret_cast<const float4*>(p + (i * 256 + t) * 4);
        s += v.x + v.y + v.z + v.w;
    }
    red[t] = s;
    __syncthreads();
    for (int off = 128; off > 0; off >>= 1) {
        if (t < off) red[t] += red[t + off];
        __syncthreads();
    }
    if (t == 0) partial[blk] = red[0];
}

// Fused per-block routing (same reduction order as standalone k_route_mix).
__device__ __forceinline__ void route_block(const float* __restrict__ partial,
                                            const float* __restrict__ rw,
                                            const float* __restrict__ rb,
                                            const float* __restrict__ wexp,
                                            int b, int c, int taps, int t,
                                            float* pool_s, float* r_s, float* w_s) {
    if (t < 64) {
        float s = 0.f;
        #pragma unroll
        for (int q = 0; q < 4; ++q) s += partial[(b * 64 + t) * 4 + q];
        pool_s[t] = s * (1.0f / 65536.0f);
    }
    __syncthreads();
    if (t < 3) {
        float z = rb[t];
        #pragma unroll
        for (int i = 0; i < 64; ++i) z += pool_s[i] * rw[t * 64 + i];
        r_s[t] = 1.0f / (1.0f + expf(-z));
    }
    __syncthreads();
    if (t < taps) {
        w_s[t] = r_s[0] * wexp[(0 * 64 + c) * taps + t] +
                 r_s[1] * wexp[(1 * 64 + c) * taps + t] +
                 r_s[2] * wexp[(2 * 64 + c) * taps + t];
    }
    __syncthreads();
}

// -------- K2: depthwise 5x5 pad2 + bias + gelu -> fp16, with tile sums --------
// (R14 version: global float4 loads, 8x8/thread, fused routing — unchanged)
__global__ __launch_bounds__(256) void k_conv5(const float* __restrict__ x,
                                               const float* __restrict__ partial,
                                               const float* __restrict__ rw,
                                               const float* __restrict__ rb,
                                               const float* __restrict__ wexp,
                                               const float* __restrict__ bias,
                                               __half* __restrict__ attn0,
                                               float* __restrict__ tilesum) {
    __shared__ float red[256];
    __shared__ float pool_s[64];
    __shared__ float r_s[3];
    __shared__ float w_s[25];
    const int blk = blockIdx.x;              // plane*4 + tile (128x128 tiles)
    const int plane = blk >> 2;
    const int tile = blk & 3;
    const int b = plane >> 6;
    const int c = plane & 63;
    const int oy0 = (tile >> 1) << 7;
    const int ox0 = (tile & 1) << 7;
    const int t = threadIdx.x;
    const int ox = ox0 + ((t & 15) << 3);    // 8-wide strip
    const int oy = oy0 + ((t >> 4) << 3);    // 8-tall
    const float* xp = x + (size_t)plane * HW;

    route_block(partial, rw, rb, wexp, b, c, 25, t, pool_s, r_s, w_s);
    float w[25];
    #pragma unroll
    for (int i = 0; i < 25; ++i) w[i] = sgpr_f(w_s[i]);

    float acc[8][8];
    #pragma unroll
    for (int i = 0; i < 8; ++i)
        #pragma unroll
        for (int j = 0; j < 8; ++j) acc[i][j] = 0.f;

    #pragma unroll
    for (int r = 0; r < 12; ++r) {
        const int gy = oy - 2 + r;
        if (gy >= 0 && gy < 256) {
            const float* rp = xp + gy * PW + ox;
            float buf[16];
            float4 v;
            if (ox > 0) v = *reinterpret_cast<const float4*>(rp - 4);
            else        v = make_float4(0.f, 0.f, 0.f, 0.f);
            buf[0] = v.x; buf[1] = v.y; buf[2] = v.z; buf[3] = v.w;
            v = *reinterpret_cast<const float4*>(rp);
            buf[4] = v.x; buf[5] = v.y; buf[6] = v.z; buf[7] = v.w;
            v = *reinterpret_cast<const float4*>(rp + 4);
            buf[8] = v.x; buf[9] = v.y; buf[10] = v.z; buf[11] = v.w;
            if (ox < 248) v = *reinterpret_cast<const float4*>(rp + 8);
            else          v = make_float4(0.f, 0.f, 0.f, 0.f);
            buf[12] = v.x; buf[13] = v.y; buf[14] = v.z; buf[15] = v.w;
            #pragma unroll
            for (int i = 0; i < 8; ++i) {
                const int d = r - i;
                if (d >= 0 && d <= 4) {
                    #pragma unroll
                    for (int dx = 0; dx < 5; ++dx) {
                        const float wv = w[d * 5 + dx];
                        #pragma unroll
                        for (int j = 0; j < 8; ++j)
                            acc[i][j] += wv * buf[j + dx + 2];
                    }
                }
            }
        }
    }
    const float bs = bias[c];
    float lsum = 0.f;
    __half* op = attn0 + (size_t)plane * HW;
    #pragma unroll
    for (int i = 0; i < 8; ++i) {
        float g[8];
        #pragma unroll
        for (int j = 0; j < 8; ++j) {
            g[j] = gelu_f(acc[i][j] + bs);
            lsum += g[j];
        }
        uint4 st;
        st.x = pack2h(g[0], g[1]); st.y = pack2h(g[2], g[3]);
        st.z = pack2h(g[4], g[5]); st.w = pack2h(g[6], g[7]);
        *reinterpret_cast<uint4*>(op + (oy + i) * PW + ox) = st;
    }
    red[t] = lsum;
    __syncthreads();
    for (int off = 128; off > 0; off >>= 1) {
        if (t < off) red[t] += red[t + off];
        __syncthreads();
    }
    if (t == 0) tilesum[blk] = red[0];
}

// -------- K4: depthwise 7x7 dil3 pad9 + bias + gelu, fp16 -> fp16 -------------
// (R15 version: dot2 row-pairing, odd-stride LDS — unchanged)
__global__ __launch_bounds__(256, 3) void k_conv7(const __half* __restrict__ a0,
                                                  const float* __restrict__ tilesum,
                                                  const float* __restrict__ rw,
                                                  const float* __restrict__ rb,
                                                  const float* __restrict__ wexp,
                                                  const float* __restrict__ bias,
                                                  __half* __restrict__ attn1) {
    __shared__ unsigned lds[82 * C7SD];      // 27880 B
    __shared__ float pool_s[64];
    __shared__ float r_s[3];
    __shared__ float w_s[49];
    const int blk = blockIdx.x;              // plane*8 + tile (64-row x 128-col)
    const int plane = blk >> 3;
    const int tile = blk & 7;
    const int b = plane >> 6;
    const int c = plane & 63;
    const int oy0 = (tile >> 1) << 6;        // 0,64,128,192
    const int ox0 = (tile & 1) << 7;         // 0,128
    const int t = threadIdx.x;
    const __half* ap = a0 + (size_t)plane * HW;

    const uint4 z4 = make_uint4(0u, 0u, 0u, 0u);
    #pragma unroll
    for (int it = 0; it < 7; ++it) {
        const int idx = it * 256 + t;
        if (idx < 1722) {                    // 82*21
            const int lr = idx / 21;
            const int c8 = idx - lr * 21;
            const int gy = oy0 - 9 + lr;
            const int gx = ox0 - 16 + (c8 << 3);
            uint4 v = z4;
            if ((unsigned)gy < 256u && (unsigned)gx < 256u)
                v = *reinterpret_cast<const uint4*>(ap + gy * PW + gx);
            unsigned* wp = &lds[lr * C7SD + (c8 << 2)];
            wp[0] = v.x; wp[1] = v.y; wp[2] = v.z; wp[3] = v.w;
        }
    }

    route_block(tilesum, rw, rb, wexp, b, c, 49, t, pool_s, r_s, w_s);
    unsigned wpk[21];
    #pragma unroll
    for (int p = 0; p < 3; ++p)
        #pragma unroll
        for (int dxi = 0; dxi < 7; ++dxi)
            wpk[p * 7 + dxi] = (unsigned)__builtin_amdgcn_readfirstlane(
                (int)pack2h(w_s[(2 * p) * 7 + dxi], w_s[(2 * p + 1) * 7 + dxi]));
    float wt[7];
    #pragma unroll
    for (int i = 0; i < 7; ++i) wt[i] = sgpr_f(w_s[42 + i]);
    __syncthreads();                         // staging complete too

    const int tx = t & 3, ty = t >> 2;       // 4 x 64
    const int ox = tx << 5;                  // 32-wide strip: 0,32,64,96
    float acc[32];
    #pragma unroll
    for (int j = 0; j < 32; ++j) acc[j] = 0.f;

    #pragma unroll
    for (int p = 0; p < 3; ++p) {
        const int rA = ty + 6 * p;
        const unsigned* lA = &lds[rA * C7SD + (tx << 4)];
        const unsigned* lB = &lds[(rA + 3) * C7SD + (tx << 4)];
        unsigned hA[32], hB[32];
        #pragma unroll
        for (int i = 0; i < 32; ++i) hA[i] = lA[i];
        #pragma unroll
        for (int i = 0; i < 32; ++i) hB[i] = lB[i];
        unsigned pr[50];
        #pragma unroll
        for (int i = 0; i < 50; ++i) {
            const int s = i + 7, k = s >> 1;
            pr[i] = __builtin_amdgcn_perm(hB[k], hA[k],
                                          (s & 1) ? 0x07060302u : 0x05040100u);
        }
        #pragma unroll
        for (int dxi = 0; dxi < 7; ++dxi) {
            const unsigned wp = wpk[p * 7 + dxi];
            #pragma unroll
            for (int j = 0; j < 32; ++j)
                dot2_h(acc[j], wp, pr[3 * dxi + j]);
        }
    }
    {
        const unsigned* lp = &lds[(ty + 18) * C7SD + (tx << 4)];
        unsigned hbuf[32];
        #pragma unroll
        for (int i = 0; i < 32; ++i) hbuf[i] = lp[i];
        #pragma unroll
        for (int dxi = 0; dxi < 7; ++dxi) {
            const float wv = wt[dxi];
            const int o = 7 + 3 * dxi;
            #pragma unroll
            for (int j = 0; j < 32; ++j) {
                const int h = o + j;
                fma_mix_h(acc[j], wv, hbuf[h >> 1], h & 1);
            }
        }
    }

    const float bs = bias[c];
    __half* op = attn1 + (size_t)plane * HW + (size_t)(oy0 + ty) * PW + ox0 + ox;
    #pragma unroll
    for (int q = 0; q < 4; ++q) {
        float g[8];
        #pragma unroll
        for (int j = 0; j < 8; ++j) g[j] = gelu_f(acc[q * 8 + j] + bs);
        uint4 st;
        st.x = pack2h(g[0], g[1]); st.y = pack2h(g[2], g[3]);
        st.z = pack2h(g[4], g[5]); st.w = pack2h(g[6], g[7]);
        *reinterpret_cast<uint4*>(op + (q << 3)) = st;
    }
}

// -------- K5: 1x1 channel mix + bias, then out = x * attn ---------------------
// 128-pixel chunks (4096 blocks): LDS 24.5 KB -> ~6 blocks/CU, A_s rows 256B
// -> 2-way conflict (free). Thread = 4 outputs x 8 pixels (acc=32).
__global__ __launch_bounds__(256) void k_mix(const __half* __restrict__ attn1,
                                             const float* __restrict__ wpm,
                                             const float* __restrict__ bp,
                                             const float* __restrict__ x,
                                             float* __restrict__ out) {
    __shared__ __half A_s[64][128];          // 16 KB
    __shared__ unsigned w2_s[32][64];        // 8 KB: (c-pair) x (o), f16x2
    const int t = threadIdx.x;
    const int blk = blockIdx.x;
    const int b = blk >> 9;
    const int p0g = (blk & 511) << 7;        // 128-pixel chunk
    #pragma unroll
    for (int it = 0; it < 4; ++it) {
        const int idx = it * 256 + t;        // 1024 uint4 = 64 rows x 16
        const int row = idx >> 4;
        const int off = (idx & 15) << 3;
        uint4 u = *reinterpret_cast<const uint4*>(attn1 + (size_t)(b * 64 + row) * HW + p0g + off);
        *reinterpret_cast<uint4*>(&A_s[row][off]) = u;
    }
    #pragma unroll
    for (int j = 0; j < 8; ++j) {
        const int idx = j * 256 + t;         // 2048 entries
        const int oo = idx >> 5;
        const int cc2 = idx & 31;
        w2_s[cc2][oo] = pack2h(wpm[oo * 64 + 2 * cc2], wpm[oo * 64 + 2 * cc2 + 1]);
    }
    __syncthreads();
    const int o0 = (t >> 4) << 2;            // 4 outputs
    const int p0 = (t & 15) << 3;            // 8 pixels
    float acc[4][8];
    #pragma unroll
    for (int i = 0; i < 4; ++i)
        #pragma unroll
        for (int j = 0; j < 8; ++j) acc[i][j] = 0.f;
    #pragma unroll 4
    for (int cc2 = 0; cc2 < 32; ++cc2) {
        uint4 a0 = *reinterpret_cast<const uint4*>(&A_s[2 * cc2][p0]);
        uint4 a1 = *reinterpret_cast<const uint4*>(&A_s[2 * cc2 + 1][p0]);
        const unsigned a0w[4] = {a0.x, a0.y, a0.z, a0.w};
        const unsigned a1w[4] = {a1.x, a1.y, a1.z, a1.w};
        unsigned pr[8];
        #pragma unroll
        for (int j = 0; j < 8; ++j)
            pr[j] = __builtin_amdgcn_perm(a1w[j >> 1], a0w[j >> 1],
                                          (j & 1) ? 0x07060302u : 0x05040100u);
        uint4 wv0 = *reinterpret_cast<const uint4*>(&w2_s[cc2][o0]);
        const unsigned wv[4] = {wv0.x, wv0.y, wv0.z, wv0.w};
        #pragma unroll
        for (int oo = 0; oo < 4; ++oo) {
            const unsigned wvv = wv[oo];
            #pragma unroll
            for (int pp = 0; pp < 8; ++pp)
                dot2_hv(acc[oo][pp], wvv, pr[pp]);
        }
    }
    #pragma unroll
    for (int oo = 0; oo < 4; ++oo) {
        const int o = o0 + oo;
        const float bb = bp[o];
        const size_t base = (size_t)(b * 64 + o) * HW + p0g + p0;
        float4 x0 = *reinterpret_cast<const float4*>(x + base);
        float4 x1 = *reinterpret_cast<const float4*>(x + base + 4);
        float4 r0, r1;
        r0.x = x0.x * (acc[oo][0] + bb); r0.y = x0.y * (acc[oo][1] + bb);
        r0.z = x0.z * (acc[oo][2] + bb); r0.w = x0.w * (acc[oo][3] + bb);
        r1.x = x1.x * (acc[oo][4] + bb); r1.y = x1.y * (acc[oo][5] + bb);
        r1.z = x1.z * (acc[oo][6] + bb); r1.w = x1.w * (acc[oo][7] + bb);
        *reinterpret_cast<float4*>(out + base) = r0;
        *reinterpret_cast<float4*>(out + base + 4) = r1;
    }
}

extern "C" void kernel_launch(void* const* d_in, const int* in_sizes, int n_in,
                              void* d_out, int out_size, void* d_ws, size_t ws_size,
                              hipStream_t stream) {
    const float* x   = (const float*)d_in[0];
    const float* w0  = (const float*)d_in[1];
    const float* b0  = (const float*)d_in[2];
    const float* r0w = (const float*)d_in[3];
    const float* r0b = (const float*)d_in[4];
    const float* w1  = (const float*)d_in[5];
    const float* b1  = (const float*)d_in[6];
    const float* r1w = (const float*)d_in[7];
    const float* r1b = (const float*)d_in[8];
    const float* wpm = (const float*)d_in[9];
    const float* bp  = (const float*)d_in[10];
    float* out = (float*)d_out;

    // workspace layout (needs ~134.3 MB)
    char* ws = (char*)d_ws;
    __half* attn0   = (__half*)(ws);                       // 64 MB
    __half* attn1   = (__half*)(ws + 67108864);            // 64 MB
    float* partial0 = (float*)(ws + 134217728);            // 2048 f32
    float* tilesum1 = (float*)(ws + 134217728 + 8192);     // 2048 f32

    k_pool_x<<<2048, 256, 0, stream>>>(x, partial0);
    k_conv5<<<2048, 256, 0, stream>>>(x, partial0, r0w, r0b, w0, b0, attn0, tilesum1);
    k_conv7<<<4096, 256, 0, stream>>>(attn0, tilesum1, r1w, r1b, w1, b1, attn1);
    k_mix<<<4096, 256, 0, stream>>>(attn1, wpm, bp, x, out);
}